// Round 8
// baseline (366.338 us; speedup 1.0000x reference)
//
#include <hip/hip_runtime.h>
#include <math.h>

#define BB 16
#define NN 512
#define HID 32

#define HALO 16
#define TW 96        // logical tile width (64 + 2*HALO)
#define TWP 97       // LDS pitch: 97 % 32 == 1 -> conflict-free Phase D
#define OT 64

// fast tanh-approx GELU: gelu(v) = v / (1 + exp2(K1*v + K2*v^3))
#define GELU_K1 (-2.302208201f)
#define GELU_K2 (-0.102944244f)

// LFA angle step 2*pi/513: rotation recurrence cos/sin
#define CDR 0.99992499f
#define SDR 0.012247618f
// 1/513 (angles in revolutions for v_sin_f32/v_cos_f32: D = sin(S0*2pi))
#define REVS 0.0019493177f

// Pub-row exchange overlay (inside sxraw, regions dead/masked during sweeps):
// band A parity p at 194 + p*2328 (slots 0..7, 98 floats each)
// band B parity p at 1358 + p*2328 (slots 0..7)
// band A slot ty = top source for reader ty (= pub of row 11, thread ty-1;
//                  slot 0 stays zero), index k = col k-1 (guard at 0/97)
// band B slot ty = bot source for reader ty (= pub of row 0, thread ty+1;
//                  slot 7 stays zero)
// Aliasing audit: bands touch sx rows 0-9/12-21/24-33/36-45; sweep-0 top/bot
// reads touch rows {-1,11,12,23,24,...,96}; intersection = col-96 cells only,
// which feed exclusively vC-masked tx==31 c=2 taps. Safe.
#define PUBA 194
#define PUBDP 2328   // parity delta (floats); bot = top + 1164; pub0 = pub11 + 968

// ---------------------------------------------------------------------------
// LFA map (R10-proven + HW sin/cos, ~5 us). MEASURED (rounds 2 & 3): folding
// this into fused_cycle in ANY form tips it to 132 VGPR. Separate. FROZEN.
// ---------------------------------------------------------------------------
__global__ __launch_bounds__(256) void lfa_kernel(const float* __restrict__ kernelA,
                                                  float* __restrict__ lfa) {
    const int t = threadIdx.x;
    const int strip = t & 127;           // 128 strips of 4 cols
    const int i = blockIdx.y * 2 + (t >> 7);
    const int b = blockIdx.z;
    const int j0 = strip * 4;
    const float* a = kernelA + b * 9;
    float a0 = a[0], a1 = a[1], a2 = a[2], a3 = a[3], a4 = a[4];
    float a5 = a[5], a6 = a[6], a7 = a[7], a8 = a[8];
    const float A35 = a3 + a5, A17 = a1 + a7, A08 = a0 + a8, A26 = a2 + a6;
    const float B53 = a5 - a3, B71 = a7 - a1, B80 = a8 - a0, B26 = a2 - a6;
    const float tau = 0.5f / a4;

    float r1 = (float)(j0 - NN / 2) * REVS;   // revolutions, |r| < 0.5
    float r2 = (float)(i - NN / 2) * REVS;
    float s1 = __builtin_amdgcn_sinf(r1);
    float c1 = __builtin_amdgcn_cosf(r1);
    float s2 = __builtin_amdgcn_sinf(r2);
    float c2 = __builtin_amdgcn_cosf(r2);

    float out[4];
#pragma unroll
    for (int k = 0; k < 4; ++k) {
        float cc = c1 * c2, ss = s1 * s2, sc = s1 * c2, cs = c1 * s2;
        float cpp = cc - ss, cpm = cc + ss, spp = sc + cs, spm = sc - cs;
        float re = fmaf(A35, c1, a4); re = fmaf(A17, c2, re);
        re = fmaf(A08, cpp, re);      re = fmaf(A26, cpm, re);
        float im = B53 * s1;          im = fmaf(B71, s2, im);
        im = fmaf(B80, spp, im);      im = fmaf(B26, spm, im);
        float zre = fmaf(-tau, re, 1.0f);
        float zim = tau * im;
        float m2 = fmaf(zre, zre, zim * zim);
        out[k] = m2 * m2 * sqrtf(m2);   // |z|^5
        float tt = s1 * SDR;
        float ns = fmaf(s1, CDR, c1 * SDR);
        c1 = fmaf(c1, CDR, -tt);
        s1 = ns;
    }
    float4 ov = {out[0], out[1], out[2], out[3]};
    *(float4*)(lfa + (size_t)b * NN * NN + (size_t)i * NN + j0) = ov;
}

// ---------------------------------------------------------------------------
// One full cycle. Round 8 = round-6 single-barrier structure with the
// MISSING STENCIL TAP RESTORED.
// POST-MORTEM (rounds 6/7): both failed with bit-identical absmax 3.906e-2.
// Cause: round 6's sweep_core dropped the c=2 SW tap (q6*n1) in an fma-chain
// compression; round 7 inherited it. NOT the pub-band overlay, NOT the
// shuffles: identical outputs across the two structures prove both halo
// delivery mechanisms are bit-equivalent. All 3 c-blocks below are written
// in the canonical 9-tap form (verbatim round-5 semantics).
//  - L/R halo via __shfl_up/down(1): neighbor lane's cur registers are the
//    previous-sweep values (lockstep), bit-exact vs round-5's LDS publish.
//    Wave-boundary garbage feeds only vC-masked cells.
//  - top/bot rows via double-buffered pub bands overlaid on dead/masked
//    sxraw space (zero extra LDS) -> ONE __syncthreads per sweep.
// Barriers/kernel: 21 -> 13 (FIRST: 11).
// Proven config: 128 VGPR, 4 waves/SIMD. DO NOT add live state near Phase
// C/D (132-VGPR cliff, +20..80 us). DO NOT use __launch_bounds__(256,4)
// (round-1: 64-VGPR bucket + spills). DO NOT inline LFA (rounds 2 & 3).
// ---------------------------------------------------------------------------
template <bool FIRST, bool RES>
__global__ __launch_bounds__(256) void fused_cycle(
        const float* __restrict__ xin, float* __restrict__ xout,
        const float* __restrict__ f, const float* __restrict__ kernelA,
        const float* __restrict__ lfa,
        const float* __restrict__ W1, const float* __restrict__ b1,
        const float* __restrict__ W2, const float* __restrict__ b2,
        float* __restrict__ accp, float* __restrict__ outp) {
    __shared__ float sxraw[98 * TWP + 2];
    float* sx = sxraw + TWP + 1;   // logical origin (0,0); row r col c -> sx[r*TWP+c]
    const int tx = threadIdx.x;   // 0..31
    const int ty = threadIdx.y;   // 0..7
    const int t  = ty * 32 + tx;
    const int b  = blockIdx.z;
    const int gy0 = blockIdx.y * OT;
    const int gx0 = blockIdx.x * OT;
    const int goi = gy0 - HALO;
    const int goj = gx0 - HALO;
    const float* fg = f + (size_t)b * NN * NN;
    const float* ag = kernelA + b * 9;   // uniform -> s_load
    const float ar0 = ag[0], ar1 = ag[1], ar2 = ag[2], ar3 = ag[3], ar4 = ag[4];
    const float ar5 = ag[5], ar6 = ag[6], ar7 = ag[7], ar8 = ag[8];
    const float tau = 0.5f / ar4;
    const float s0 = tau * ar0, q1 = tau * ar1, q2 = tau * ar2, q3 = tau * ar3;
    const float q4 = tau * ar4, q5 = tau * ar5, q6 = tau * ar6, q7 = tau * ar7;
    const float q8 = tau * ar8;

    if (FIRST) {
        if (t == 0 && (blockIdx.x | blockIdx.y | blockIdx.z) == 0) {
            accp[0] = 0.f;
            accp[1] = 0.f;
            ((unsigned int*)accp)[2] = 0u;
        }
    }

    // zero the pub-band guards (both parities): band-A slot 0 (top of ty=0),
    // band-B slot 7 (bot of ty=7), col guards k=0/97 of the data slots.
    auto pub_zero = [&]() {
        for (int idx = t; idx < 448; idx += 256) {
            int p = (idx >= 224) ? 1 : 0;
            int j = idx - (p ? 224 : 0);
            int off;
            if (j < 98) off = PUBA + j;                    // band A slot 0
            else if (j < 196) off = 2044 + (j - 98);       // band B slot 7
            else {
                int g = j - 196;                           // 0..27 col guards
                int s, base;
                if (g < 14) { base = PUBA; s = 1 + (g >> 1); }
                else        { base = 1358; s = (g - 14) >> 1; }
                off = base + s * 98 + ((g & 1) ? 97 : 0);
            }
            sxraw[off + (p ? PUBDP : 0)] = 0.f;
        }
    };

    if (!FIRST) {
        // sx guard ring (needed for sweep-0 halo reads)
        if (t < 98) sxraw[t] = 0.f;
        if (t < 96) sxraw[97 + 97 * t] = 0.f;
        if (t < 98) sxraw[9409 + t] = 0.f;
        // Phase A: tile -> LDS, float4 strips (round-5 proven)
        const float* xg = xin + (size_t)b * NN * NN;
#pragma unroll
        for (int k = 0; k < 9; ++k) {
            int idx = t + k * 256;
            int row = idx / 24;
            int c4  = (idx - row * 24) * 4;
            int gi = goi + row, gj = goj + c4;
            float4 v = {0.f, 0.f, 0.f, 0.f};
            if ((unsigned)gi < NN && (unsigned)gj < NN)
                v = *(const float4*)(xg + (size_t)gi * NN + gj);
            float* d = sx + row * TWP + c4;
            d[0] = v.x; d[1] = v.y; d[2] = v.z; d[3] = v.w;
        }
    } else {
        pub_zero();   // FIRST: sx is untouched until the final publish
    }

    const int R0 = ty * 12, C0 = tx * 3;
    const float* pb  = sx + (R0 - 1) * TWP + (C0 - 1);
    float*       pwv = sx + R0 * TWP + C0;
    float*       PT  = sxraw + PUBA + ty * 98 + C0;   // parity-0 top-read base

    float vR[12], vC[3];
#pragma unroll
    for (int r = 0; r < 12; ++r) {
        int R = R0 + r, gi = goi + R;
        vR[r] = (R >= 1 && R < TW - 1 && gi >= 0 && gi < NN) ? 1.f : 0.f;
    }
#pragma unroll
    for (int c = 0; c < 3; ++c) {
        int C = C0 + c, gj = goj + C;
        vC[c] = (C >= 1 && C < TW - 1 && gj >= 0 && gj < NN) ? 1.f : 0.f;
    }

    float frt[12][3];
#pragma unroll
    for (int r = 0; r < 12; ++r) {
        int gi = goi + R0 + r;
#pragma unroll
        for (int c = 0; c < 3; ++c) {
            int gj = goj + C0 + c;
            frt[r][c] = (gi >= 0 && gi < NN && gj >= 0 && gj < NN)
                            ? tau * fg[gi * NN + gj] : 0.f;
        }
    }

    float cur[12][3];

    // one Jacobi sweep; L/R via wave shuffles. CANONICAL 9-TAP FORM — do not
    // compress the fma chains (rounds 6/7 lost the q6*n1 tap doing that).
    auto sweep_core = [&](float top0, float top1, float top2, float top3, float top4,
                          float bot0, float bot1, float bot2, float bot3, float bot4) {
        float pm0 = top1, pm1v = top2, pm2 = top3;
        float Lm1 = top0, Rm1 = top4;
        float Lc = __shfl_up(cur[0][2], 1);
        float Rc = __shfl_down(cur[0][0], 1);
#pragma unroll
        for (int r = 0; r < 12; ++r) {
            float n0, n1, n2, Lp, Rp;
            if (r < 11) {
                n0 = cur[r + 1][0]; n1 = cur[r + 1][1]; n2 = cur[r + 1][2];
                Lp = __shfl_up(cur[r + 1][2], 1);
                Rp = __shfl_down(cur[r + 1][0], 1);
            } else {
                n0 = bot1; n1 = bot2; n2 = bot3; Lp = bot0; Rp = bot4;
            }
            float o0 = cur[r][0], o1 = cur[r][1], o2 = cur[r][2];
            // c = 0
            {
                float ax = s0 * Lm1;
                ax = fmaf(q1, pm0, ax); ax = fmaf(q2, pm1v, ax);
                ax = fmaf(q3, Lc, ax);  ax = fmaf(q4, o0, ax);
                ax = fmaf(q5, o1, ax);  ax = fmaf(q6, Lp, ax);
                ax = fmaf(q7, n0, ax);  ax = fmaf(q8, n1, ax);
                cur[r][0] = fmaf(vR[r] * vC[0], frt[r][0] - ax, o0);
            }
            // c = 1
            {
                float ax = s0 * pm0;
                ax = fmaf(q1, pm1v, ax); ax = fmaf(q2, pm2, ax);
                ax = fmaf(q3, o0, ax);   ax = fmaf(q4, o1, ax);
                ax = fmaf(q5, o2, ax);   ax = fmaf(q6, n0, ax);
                ax = fmaf(q7, n1, ax);   ax = fmaf(q8, n2, ax);
                cur[r][1] = fmaf(vR[r] * vC[1], frt[r][1] - ax, o1);
            }
            // c = 2
            {
                float ax = s0 * pm1v;
                ax = fmaf(q1, pm2, ax); ax = fmaf(q2, Rm1, ax);
                ax = fmaf(q3, o1, ax);  ax = fmaf(q4, o2, ax);
                ax = fmaf(q5, Rc, ax);  ax = fmaf(q6, n1, ax);
                ax = fmaf(q7, n2, ax);  ax = fmaf(q8, Rp, ax);
                cur[r][2] = fmaf(vR[r] * vC[2], frt[r][2] - ax, o2);
            }
            pm0 = o0; pm1v = o1; pm2 = o2;
            Lm1 = Lc; Rm1 = Rc; Lc = Lp; Rc = Rp;
        }
    };

    // publish rows 11/0 into the pub bands; wB = band-A target (reader ty+1),
    // wB+968 = band-B target (reader ty-1)
    auto pub_rows = [&](float* wB) {
        if (ty < 7) { wB[0] = cur[11][0]; wB[1] = cur[11][1]; wB[2] = cur[11][2]; }
        if (ty > 0) { wB[968] = cur[0][0]; wB[969] = cur[0][1]; wB[970] = cur[0][2]; }
    };

    // ---- sweep 0 ----
    if (FIRST) {
        // collapsed: x1 = mask * (tau*f)
#pragma unroll
        for (int r = 0; r < 12; ++r)
#pragma unroll
            for (int c = 0; c < 3; ++c)
                cur[r][c] = (vR[r] * vC[c]) * frt[r][c];
    } else {
        __syncthreads();   // (1) tile visible
#pragma unroll
        for (int r = 0; r < 12; ++r) {
            cur[r][0] = pwv[r * TWP];
            cur[r][1] = pwv[r * TWP + 1];
            cur[r][2] = pwv[r * TWP + 2];
        }
        __syncthreads();   // (2) all tile reads done before pub writes
        pub_zero();
        // real sweep 0: top/bot straight from sx (rows R0-1 / R0+12; the pub
        // bands alias these rows only at col-96 cells, which feed exclusively
        // vC-masked tx==31 taps)
        sweep_core(pb[0], pb[1], pb[2], pb[3], pb[4],
                   pb[13 * TWP], pb[13 * TWP + 1], pb[13 * TWP + 2],
                   pb[13 * TWP + 3], pb[13 * TWP + 4]);
    }
    pub_rows(PT + 99);     // parity 0
    __syncthreads();       // (3)/(1)

    // ---- sweeps 1..8: one barrier each ----
    int e = PUBDP;
    for (int s = 1; s < 9; ++s) {
        sweep_core(PT[0], PT[1], PT[2], PT[3], PT[4],
                   PT[1164], PT[1165], PT[1166], PT[1167], PT[1168]);
        pub_rows(PT + 99 + e);
        PT += e; e = -e;
        __syncthreads();
    }

    // ---- sweep 9: publish ALL cells for the correction phase ----
    sweep_core(PT[0], PT[1], PT[2], PT[3], PT[4],
               PT[1164], PT[1165], PT[1166], PT[1167], PT[1168]);
    __syncthreads();   // all pub-band reads done (full publish overwrites bands)
#pragma unroll
    for (int r = 0; r < 12; ++r) {
        pwv[r * TWP] = cur[r][0];
        pwv[r * TWP + 1] = cur[r][1];
        pwv[r * TWP + 2] = cur[r][2];
    }
    __syncthreads();   // writes visible

    // ---- Phase D: remapped correction, exactly 1x MLP work ----
    const int orow = t >> 2;
    const int oseg = t & 3;
    const int Rl = HALO + orow;           // 16..79
    const int Cl0 = HALO + oseg * 16;     // 16,32,48,64
    const float* pw = sx + (Rl - 1) * TWP + (Cl0 - 1);
    const int gi = gy0 + orow;
    const int gjb = gx0 + oseg * 16;
    const float b2v = b2[0];

    if (!RES) {
        float w0[18], w1[18], w2[18];
#pragma unroll
        for (int k = 0; k < 18; ++k) {
            w0[k] = pw[k];
            w1[k] = pw[TWP + k];
            w2[k] = pw[2 * TWP + k];
        }
        const float4* f4 = (const float4*)(fg + (size_t)gi * NN + gjb);
        const float4* l4 = (const float4*)(lfa + (size_t)b * NN * NN + (size_t)gi * NN + gjb);
        float fv[16], lv[16];
#pragma unroll
        for (int q = 0; q < 4; ++q) {
            float4 fq = f4[q], lq = l4[q];
            fv[q * 4] = fq.x; fv[q * 4 + 1] = fq.y; fv[q * 4 + 2] = fq.z; fv[q * 4 + 3] = fq.w;
            lv[q * 4] = lq.x; lv[q * 4 + 1] = lq.y; lv[q * 4 + 2] = lq.z; lv[q * 4 + 3] = lq.w;
        }
        float rv[16];
#pragma unroll
        for (int k = 0; k < 16; ++k) {
            float ax = ar0 * w0[k];
            ax = fmaf(ar1, w0[k + 1], ax); ax = fmaf(ar2, w0[k + 2], ax);
            ax = fmaf(ar3, w1[k], ax);     ax = fmaf(ar4, w1[k + 1], ax);
            ax = fmaf(ar5, w1[k + 2], ax); ax = fmaf(ar6, w2[k], ax);
            ax = fmaf(ar7, w2[k + 1], ax); ax = fmaf(ar8, w2[k + 2], ax);
            rv[k] = fv[k] - ax;
        }
        float acc[16];
#pragma unroll
        for (int k = 0; k < 16; ++k) acc[k] = 0.f;
        for (int hh = 0; hh < HID; ++hh) {
            float w1a = W1[2 * hh], w1b = W1[2 * hh + 1], bb = b1[hh], wo = W2[hh];
#pragma unroll
            for (int k = 0; k < 16; ++k) {
                float v = fmaf(w1a, lv[k], fmaf(w1b, rv[k], bb));
                float m = v * fmaf(GELU_K2, v * v, GELU_K1);
                float e2 = __builtin_amdgcn_exp2f(m);
                float g = v * __builtin_amdgcn_rcpf(1.0f + e2);
                acc[k] = fmaf(wo, g, acc[k]);
            }
        }
        float4* xo4 = (float4*)(xout + (size_t)b * NN * NN + (size_t)gi * NN + gjb);
#pragma unroll
        for (int q = 0; q < 4; ++q) {
            float4 ov;
            ov.x = w1[q * 4 + 1] + acc[q * 4] + b2v;
            ov.y = w1[q * 4 + 2] + acc[q * 4 + 1] + b2v;
            ov.z = w1[q * 4 + 3] + acc[q * 4 + 2] + b2v;
            ov.w = w1[q * 4 + 4] + acc[q * 4 + 3] + b2v;
            xo4[q] = ov;
        }
    } else {
        // register-light residual path (rounds 2/4/5 verified)
        float rv[16];
        {
            float w[18];
#pragma unroll
            for (int k = 0; k < 18; ++k) w[k] = pw[k];
#pragma unroll
            for (int k = 0; k < 16; ++k) {
                float ax = ar0 * w[k];
                ax = fmaf(ar1, w[k + 1], ax);
                rv[k] = fmaf(ar2, w[k + 2], ax);
            }
#pragma unroll
            for (int k = 0; k < 18; ++k) w[k] = pw[TWP + k];
#pragma unroll
            for (int k = 0; k < 16; ++k) {
                float ax = fmaf(ar3, w[k], rv[k]);
                ax = fmaf(ar4, w[k + 1], ax);
                rv[k] = fmaf(ar5, w[k + 2], ax);
            }
#pragma unroll
            for (int k = 0; k < 18; ++k) w[k] = pw[2 * TWP + k];
#pragma unroll
            for (int k = 0; k < 16; ++k) {
                float ax = fmaf(ar6, w[k], rv[k]);
                ax = fmaf(ar7, w[k + 1], ax);
                rv[k] = fmaf(ar8, w[k + 2], ax);
            }
        }
        float f2 = 0.f;
        {
            const float4* f4 = (const float4*)(fg + (size_t)gi * NN + gjb);
#pragma unroll
            for (int q = 0; q < 4; ++q) {
                float4 fq = f4[q];
                rv[q * 4]     = fq.x - rv[q * 4];
                rv[q * 4 + 1] = fq.y - rv[q * 4 + 1];
                rv[q * 4 + 2] = fq.z - rv[q * 4 + 2];
                rv[q * 4 + 3] = fq.w - rv[q * 4 + 3];
                f2 = fmaf(fq.x, fq.x, f2);
                f2 = fmaf(fq.y, fq.y, f2);
                f2 = fmaf(fq.z, fq.z, f2);
                f2 = fmaf(fq.w, fq.w, f2);
            }
        }

        float Hr0 = 0.f, Hr1 = 0.f;
        int hoff0 = 0, hoff1 = 0;
        auto ringH = [&](int rc, float& Hv, int& hoff) {
            int R, C;
            if (rc < 66)       { R = 15; C = 15 + rc; }
            else if (rc < 132) { R = 80; C = rc - 51; }
            else if (rc < 196) { R = rc - 116; C = 15; }
            else               { R = rc - 180; C = 80; }
            hoff = R * TWP + C;
            int rgi = goi + R, rgj = goj + C;
            Hv = 0.f;
            if (rgi >= 0 && rgi < NN && rgj >= 0 && rgj < NN) {
                const float* pr = sx + (R - 1) * TWP + (C - 1);
                float u0 = pr[0], u1 = pr[1], u2 = pr[2];
                float m0 = pr[TWP], m1 = pr[TWP + 1], m2 = pr[TWP + 2];
                float d0 = pr[2 * TWP], d1 = pr[2 * TWP + 1], d2 = pr[2 * TWP + 2];
                float ax = ar0 * u0;
                ax = fmaf(ar1, u1, ax); ax = fmaf(ar2, u2, ax);
                ax = fmaf(ar3, m0, ax); ax = fmaf(ar4, m1, ax);
                ax = fmaf(ar5, m2, ax); ax = fmaf(ar6, d0, ax);
                ax = fmaf(ar7, d1, ax); ax = fmaf(ar8, d2, ax);
                float rp = fg[(size_t)rgi * NN + rgj] - ax;
                float lf = lfa[(size_t)b * NN * NN + (size_t)rgi * NN + rgj];
                float av = 0.f;
                for (int hh = 0; hh < HID; ++hh) {
                    float w1a = W1[2 * hh], w1b = W1[2 * hh + 1], bbv = b1[hh], wo = W2[hh];
                    float v = fmaf(w1a, lf, fmaf(w1b, rp, bbv));
                    float m = v * fmaf(GELU_K2, v * v, GELU_K1);
                    float e2 = __builtin_amdgcn_exp2f(m);
                    float gg = v * __builtin_amdgcn_rcpf(1.0f + e2);
                    av = fmaf(wo, gg, av);
                }
                Hv = av + b2v;
            }
        };
        ringH(t, Hr0, hoff0);
        if (t < 4) ringH(t + 256, Hr1, hoff1);

        float acc[16];
#pragma unroll
        for (int k = 0; k < 16; ++k) acc[k] = 0.f;
        {
            float lv[16];
            const float4* l4 = (const float4*)(lfa + (size_t)b * NN * NN + (size_t)gi * NN + gjb);
#pragma unroll
            for (int q = 0; q < 4; ++q) {
                float4 lq = l4[q];
                lv[q * 4] = lq.x; lv[q * 4 + 1] = lq.y;
                lv[q * 4 + 2] = lq.z; lv[q * 4 + 3] = lq.w;
            }
            for (int hh = 0; hh < HID; ++hh) {
                float w1a = W1[2 * hh], w1b = W1[2 * hh + 1], bb = b1[hh], wo = W2[hh];
#pragma unroll
                for (int k = 0; k < 16; ++k) {
                    float v = fmaf(w1a, lv[k], fmaf(w1b, rv[k], bb));
                    float m = v * fmaf(GELU_K2, v * v, GELU_K1);
                    float e2 = __builtin_amdgcn_exp2f(m);
                    float g = v * __builtin_amdgcn_rcpf(1.0f + e2);
                    acc[k] = fmaf(wo, g, acc[k]);
                }
            }
        }

        __syncthreads();   // all LDS w-reads (own + ring) complete
        float* ph = sx + Rl * TWP + Cl0;
#pragma unroll
        for (int k = 0; k < 16; ++k) ph[k] = acc[k] + b2v;
        sx[hoff0] = Hr0;
        if (t < 4) sx[hoff1] = Hr1;
        __syncthreads();   // H tile visible

        float rr = 0.f;
        {
            float hr[18];
#pragma unroll
            for (int k = 0; k < 18; ++k) hr[k] = pw[k];
#pragma unroll
            for (int k = 0; k < 16; ++k) {
                float ax = ar0 * hr[k];
                ax = fmaf(ar1, hr[k + 1], ax);
                ax = fmaf(ar2, hr[k + 2], ax);
                rv[k] -= ax;
            }
#pragma unroll
            for (int k = 0; k < 18; ++k) hr[k] = pw[TWP + k];
#pragma unroll
            for (int k = 0; k < 16; ++k) {
                float ax = ar3 * hr[k];
                ax = fmaf(ar4, hr[k + 1], ax);
                ax = fmaf(ar5, hr[k + 2], ax);
                rv[k] -= ax;
            }
#pragma unroll
            for (int k = 0; k < 18; ++k) hr[k] = pw[2 * TWP + k];
#pragma unroll
            for (int k = 0; k < 16; ++k) {
                float ax = ar6 * hr[k];
                ax = fmaf(ar7, hr[k + 1], ax);
                ax = fmaf(ar8, hr[k + 2], ax);
                float r = rv[k] - ax;
                rr = fmaf(r, r, rr);
            }
        }
#pragma unroll
        for (int off = 32; off > 0; off >>= 1) {
            rr += __shfl_down(rr, off, 64);
            f2 += __shfl_down(f2, off, 64);
        }
        if ((t & 63) == 0) { sxraw[t >> 6] = rr; sxraw[4 + (t >> 6)] = f2; }
        __syncthreads();
        if (t == 0) {
            atomicAdd(&accp[0], sxraw[0] + sxraw[1] + sxraw[2] + sxraw[3]);
            atomicAdd(&accp[1], sxraw[4] + sxraw[5] + sxraw[6] + sxraw[7]);
            __threadfence();
            unsigned int done = atomicAdd((unsigned int*)accp + 2, 1u);
            if (done == (NN / OT) * (NN / OT) * BB - 1) {
                __threadfence();
                float rrt = atomicAdd(&accp[0], 0.f);
                float fft = atomicAdd(&accp[1], 0.f);
                outp[0] = sqrtf(rrt / fft);
            }
        }
    }
}

// ---------------------------------------------------------------------------
extern "C" void kernel_launch(void* const* d_in, const int* in_sizes, int n_in,
                              void* d_out, int out_size, void* d_ws, size_t ws_size,
                              hipStream_t stream) {
    const float* f  = (const float*)d_in[0];
    const float* kA = (const float*)d_in[1];
    float*       u  = (float*)d_in[2];   // scratch (fully overwritten by cycle 2)
    const float* W1 = (const float*)d_in[3];
    const float* b1 = (const float*)d_in[4];
    const float* W2 = (const float*)d_in[5];
    const float* b2 = (const float*)d_in[6];
    float* out = (float*)d_out;

    char* ws = (char*)d_ws;
    float* acc = (float*)ws;                                     // 12 B
    float* xB  = (float*)(ws + 256);                             // 16 MiB
    float* lfa = (float*)(ws + 256 + (size_t)BB * NN * NN * 4);  // 16 MiB

    lfa_kernel<<<dim3(1, NN / 2, BB), 256, 0, stream>>>(kA, lfa);

    dim3 jblk(32, 8);
    dim3 jgrd(NN / OT, NN / OT, BB);

    fused_cycle<true,  false><<<jgrd, jblk, 0, stream>>>(u, xB, f, kA, lfa, W1, b1, W2, b2, acc, out);
    fused_cycle<false, false><<<jgrd, jblk, 0, stream>>>(xB, u, f, kA, lfa, W1, b1, W2, b2, acc, out);
    fused_cycle<false, true ><<<jgrd, jblk, 0, stream>>>(u, xB, f, kA, lfa, W1, b1, W2, b2, acc, out);
}